// Round 10
// baseline (134.008 us; speedup 1.0000x reference)
//
#include <hip/hip_runtime.h>
#include <hip/hip_cooperative_groups.h>

namespace cg = cooperative_groups;

#define EPSQ 1e-8f

typedef int v4i  __attribute__((ext_vector_type(4)));
typedef int v16i __attribute__((ext_vector_type(16)));

// x: (32, 32, 192, 192) f32; weight: (32, 32, 3, 3) f32; bias: (32,) f32; bits: (32,) i32
//
// Integer-exact decomposition (per batch n with group g, σ=2^(b-1)):
//   x_q = mn + s·k,  w_q = wm + t·j,  kc = k−σ, jc = j−σ  (i8, centered)
//   y[p,co] = s·t·KJ[p,co] + s·(wm+σt)·K1[p] + Tbl[class(p)][co]
//   KJ = Σ_{taps,ci} kc·jc  (i8 MFMA, exact i32; pad kc=0)
//   K1 = Σ_{taps,ci} kc     (box sum of per-pixel ci-sums; pad 0)
// k and j use the same IEEE f32 div + rintf as the reference → identical quant decisions.
//
// r10: single cooperative mega-kernel, 3 phases with grid.sync(), 777 blocks
// (= 3 balanced iterations per phase). Phase math identical to r9 (absmax 0.125).

__device__ __forceinline__ int bytesum4(int v) {
#if __has_builtin(__builtin_amdgcn_sdot4)
    return __builtin_amdgcn_sdot4(v, 0x01010101, 0, false);
#else
    return (int)(char)(v) + (int)(char)(v >> 8) + (int)(char)(v >> 16) + (int)(char)(v >> 24);
#endif
}

// ===================== Phase A: x min/max partials (2304 units) + weight codes (27 units) =====================
// partials[(batch*72+blk)*2 + {0,1}], blk in [0,72) of 16384 elems.
__device__ __forceinline__ void phaseA_unit(
    int u, int tid, const float* __restrict__ x, const float* __restrict__ w,
    float* __restrict__ partials, unsigned int* __restrict__ wq8,
    int* __restrict__ colJ, float* __restrict__ wstats, char* smem)
{
    float* smn  = (float*)smem;          // 256 f
    float* smx  = (float*)(smem + 1024); // 256 f
    int*   jred = (int*)(smem + 2048);   // 256 i
    float* swst = (float*)(smem + 3072); // 2 f

    if (u < 2304) {
        const int batch = u / 72;
        const int blk   = u % 72;
        const float4* xb4 = (const float4*)(x + (size_t)batch * 1179648 + (size_t)blk * 16384);
        float mn = INFINITY, mx = -INFINITY;
#pragma unroll
        for (int i = 0; i < 16; ++i) {
            const float4 v = xb4[i * 256 + tid];
            mn = fminf(mn, fminf(fminf(v.x, v.y), fminf(v.z, v.w)));
            mx = fmaxf(mx, fmaxf(fmaxf(v.x, v.y), fmaxf(v.z, v.w)));
        }
        smn[tid] = mn; smx[tid] = mx;
        __syncthreads();
        for (int s = 128; s > 0; s >>= 1) {
            if (tid < s) {
                smn[tid] = fminf(smn[tid], smn[tid + s]);
                smx[tid] = fmaxf(smx[tid], smx[tid + s]);
            }
            __syncthreads();
        }
        if (tid == 0) {
            partials[u * 2 + 0] = smn[0];
            partials[u * 2 + 1] = smx[0];
        }
        __syncthreads();
        return;
    }

    // weight unit: one per (g, tap)
    const int wb  = u - 2304;
    const int g   = wb / 9;
    const int tap = wb % 9;

    float wmn = INFINITY, wmx = -INFINITY;
    for (int i = tid; i < 9216; i += 256) {
        const float v = w[i];
        wmn = fminf(wmn, v); wmx = fmaxf(wmx, v);
    }
    smn[tid] = wmn; smx[tid] = wmx; __syncthreads();
    for (int s = 128; s > 0; s >>= 1) {
        if (tid < s) {
            smn[tid] = fminf(smn[tid], smn[tid + s]);
            smx[tid] = fmaxf(smx[tid], smx[tid + s]);
        }
        __syncthreads();
    }
    if (tid == 0) { swst[0] = smn[0]; swst[1] = smx[0]; }
    __syncthreads();
    if (wb == 0 && tid == 0) { wstats[0] = swst[0]; wstats[1] = swst[1]; }

    const float wmv = swst[0], wxv = swst[1];
    const int bval = 2 << g;
    const float denom = (float)((1 << bval) - 1);
    const float t = fmaxf((wxv - wmv) / denom, EPSQ);
    const int sig = 1 << (bval - 1);

    const int co = tid & 31;
    const int q  = tid >> 5;
    unsigned int packed = 0;
    int jsum = 0;
#pragma unroll
    for (int b = 0; b < 4; ++b) {
        const int ci = q * 4 + b;
        int jc = (int)rintf((w[co * 288 + ci * 9 + tap] - wmv) / t) - sig;  // IEEE div, as ref
        jc = jc < -128 ? -128 : (jc > 127 ? 127 : jc);
        jsum += jc;
        packed |= ((unsigned int)(unsigned char)(char)jc) << (8 * b);
    }
    const int lane_ = (q >> 2) * 32 + co;
    const int a4    = q & 3;
    wq8[((size_t)(g * 9 + tap) * 64 + lane_) * 4 + a4] = packed;

    jred[tid] = jsum; __syncthreads();
    if (tid < 128) jred[tid] += jred[tid + 128];
    __syncthreads();
    if (tid < 64) jred[tid] += jred[tid + 64];
    __syncthreads();
    if (tid < 32) colJ[g * 288 + tap * 32 + tid] = jred[tid] + jred[tid + 32];
    __syncthreads();
}

// ===================== Phase Q: quantize x to channel-last i8 codes (2304 units of 512 px) =====================
__device__ __forceinline__ void phaseQ_unit(
    int u, int tid, const float* __restrict__ x, const int* __restrict__ bits,
    const float* __restrict__ partials, unsigned int* __restrict__ codes, char* smem)
{
    float* bmn = (float*)smem;          // 32 f
    float* bmx = (float*)(smem + 128);  // 32 f
    float* s2  = (float*)(smem + 256);  // 2 f

    const int n     = u / 72;
    const int chunk = u % 72;
    const int bval  = bits[n];
    const int sig   = 1 << (bval - 1);

    if (tid < 32) {
        float mn = INFINITY, mx = -INFINITY;
        for (int i = 0; i < 72; ++i) {
            mn = fminf(mn, partials[(tid * 72 + i) * 2 + 0]);
            mx = fmaxf(mx, partials[(tid * 72 + i) * 2 + 1]);
        }
        bmn[tid] = mn; bmx[tid] = mx;
    }
    __syncthreads();
    if (tid == 0) {
        float mn = INFINITY, mx = -INFINITY;
        for (int nb = 0; nb < 32; ++nb)
            if (bits[nb] == bval) { mn = fminf(mn, bmn[nb]); mx = fmaxf(mx, bmx[nb]); }
        const float denom = (float)((1 << bval) - 1);
        s2[0] = mn;
        s2[1] = fmaxf((mx - mn) / denom, EPSQ);
    }
    __syncthreads();
    const float mn = s2[0], s = s2[1];

    const int px0 = chunk * 512 + tid * 2;
    const float* xn = x + (size_t)n * 1179648;

    unsigned int creg[16];
#pragma unroll
    for (int i = 0; i < 16; ++i) creg[i] = 0;

#pragma unroll
    for (int ci = 0; ci < 32; ++ci) {
        const float2 v = *(const float2*)(xn + (size_t)ci * 36864 + px0);
        const float vv[2] = {v.x, v.y};
#pragma unroll
        for (int p = 0; p < 2; ++p) {
            // IEEE f32 div + rintf: identical quant decisions to reference
            int kq = (int)rintf((vv[p] - mn) / s) - sig;
            kq = kq < -128 ? -128 : (kq > 127 ? 127 : kq);
            creg[p * 8 + (ci >> 2)] |= ((unsigned int)(unsigned char)(char)kq) << (8 * (ci & 3));
        }
    }

    unsigned int* cp = codes + ((size_t)n * 36864 + (size_t)px0) * 8;
#pragma unroll
    for (int p = 0; p < 2; ++p) {
        *(v4i*)(cp + p * 8 + 0) = (v4i){(int)creg[p*8+0], (int)creg[p*8+1], (int)creg[p*8+2], (int)creg[p*8+3]};
        *(v4i*)(cp + p * 8 + 4) = (v4i){(int)creg[p*8+4], (int)creg[p*8+5], (int)creg[p*8+6], (int)creg[p*8+7]};
    }
    __syncthreads();
}

// ===================== Phase C: i8-MFMA conv (2304 tiles of 16 rows x 32 cols) =====================
__device__ __forceinline__ void phaseC_tile(
    int t, int tid, const unsigned int* __restrict__ codes, const int* __restrict__ bits,
    const float* __restrict__ partials, const int* __restrict__ colJ,
    const float* __restrict__ wstats, const float* __restrict__ bias,
    const unsigned int* __restrict__ wq8, float* __restrict__ out, char* smem)
{
    v4i*   xkv  = (v4i*)smem;                   // 29376 B
    short* cs2s = (short*)(smem + 29376);       // 1224 B
    float* tlds = (float*)(smem + 30600);       // 1152 B
    float* bmn  = (float*)(smem + 31752);       // 128 B
    float* bmx  = (float*)(smem + 31880);       // 128 B
    float* sst  = (float*)(smem + 32008);       // 16 B : gmn, gs, C1, C2

    const int bx = t % 6;
    const int by = (t / 6) % 12;
    const int n  = t / 72;
    const int oy = by * 16;
    const int ox = bx * 32;
    const int lane = tid & 63;
    const int wv   = tid >> 6;

    const int bval = bits[n];
    const int g = (bval == 2) ? 0 : (bval == 4 ? 1 : 2);
    const int sig = 1 << (bval - 1);
    const float denom = (float)((1 << bval) - 1);

    // ---- group stats (identical ops to r9) ----
    if (tid < 32) {
        float mn = INFINITY, mx = -INFINITY;
        for (int i = 0; i < 72; ++i) {
            mn = fminf(mn, partials[(tid * 72 + i) * 2 + 0]);
            mx = fmaxf(mx, partials[(tid * 72 + i) * 2 + 1]);
        }
        bmn[tid] = mn; bmx[tid] = mx;
    }
    __syncthreads();
    if (tid == 0) {
        float mn = INFINITY, mx = -INFINITY;
        for (int nb = 0; nb < 32; ++nb)
            if (bits[nb] == bval) { mn = fminf(mn, bmn[nb]); mx = fmaxf(mx, bmx[nb]); }
        const float scale = fmaxf((mx - mn) / denom, EPSQ);
        const float wmv = wstats[0], wxv = wstats[1];
        const float tq = fmaxf((wxv - wmv) / denom, EPSQ);
        const double B_ = (double)wmv + (double)sig * (double)tq;
        sst[0] = mn;
        sst[1] = scale;
        sst[2] = (float)((double)scale * (double)tq);   // C1
        sst[3] = (float)((double)scale * B_);           // C2
    }
    __syncthreads();
    const float C1 = sst[2];
    const float C2 = sst[3];

    // ---- Tbl inline (exact r9 f64 math) ----
    {
        const float wmv = wstats[0], wxv = wstats[1];
        const float tq = fmaxf((wxv - wmv) / denom, EPSQ);
        const double A_ = (double)sst[0] + (double)sig * (double)sst[1];
        const double B_ = (double)wmv + (double)sig * (double)tq;
        for (int idx = tid; idx < 288; idx += 256) {
            const int cls = idx / 32;
            const int co  = idx % 32;
            const int rc = cls / 3, cc = cls % 3;
            double js = 0.0, ij = 0.0; int ninv = 0;
            for (int tap = 0; tap < 9; ++tap) {
                const int dy = tap / 3, dx = tap % 3;
                const int cj = colJ[g * 288 + tap * 32 + co];
                js += (double)cj;
                const bool inv = (rc == 0 && dy == 0) || (rc == 2 && dy == 2) ||
                                 (cc == 0 && dx == 0) || (cc == 2 && dx == 2);
                if (inv) { ++ninv; ij += (double)cj; }
            }
            const double v = (double)tq * A_ * js + 288.0 * A_ * B_ + (double)bias[co]
                           - A_ * (32.0 * B_ * (double)ninv + (double)tq * ij);
            tlds[idx] = (float)v;
        }
    }

    // ---- weights -> registers (9 A-frags) ----
    const v4i* wA = (const v4i*)(wq8 + (size_t)g * 2304);
    v4i wfr[9];
#pragma unroll
    for (int tt = 0; tt < 9; ++tt) wfr[tt] = wA[tt * 64 + lane];

    // ---- stage codes (pad -> 0) ----
    const unsigned int* cb = codes + (size_t)n * 36864 * 8;
    char* xk = (char*)xkv;
    for (int px = tid; px < 612; px += 256) {
        const int r = px / 34;
        const int c = px - r * 34;
        const int gy = oy + r - 1, gx = ox + c - 1;
        v4i pk0 = (v4i){0,0,0,0}, pk1 = (v4i){0,0,0,0};
        int ksum = 0;
        if (((unsigned)gy < 192u) && ((unsigned)gx < 192u)) {
            const unsigned int* p = cb + ((size_t)gy * 192 + gx) * 8;
            pk0 = *(const v4i*)(p + 0);
            pk1 = *(const v4i*)(p + 4);
            ksum = bytesum4(pk0.x) + bytesum4(pk0.y) + bytesum4(pk0.z) + bytesum4(pk0.w)
                 + bytesum4(pk1.x) + bytesum4(pk1.y) + bytesum4(pk1.z) + bytesum4(pk1.w);
        }
        *(v4i*)(xk + px * 48 +  0) = pk0;
        *(v4i*)(xk + px * 48 + 16) = pk1;
        cs2s[px] = (short)ksum;
    }
    __syncthreads();

    // ---- MFMA conv + epilogue (one 4-row quad per wave) ----
    const int c  = lane & 31;
    const int ch = lane >> 5;
    const int gx = ox + c;
    const int cc = (gx == 0) ? 0 : ((gx == 191) ? 2 : 1);
    const int r0 = wv * 4;

    v16i acc[4] = {};
#pragma unroll
    for (int dyr = 0; dyr < 6; ++dyr) {
        const int xrow = r0 + dyr;
        const v4i bf0 = xkv[(xrow * 34 + c + 0) * 3 + ch];
        const v4i bf1 = xkv[(xrow * 34 + c + 1) * 3 + ch];
        const v4i bf2 = xkv[(xrow * 34 + c + 2) * 3 + ch];
#pragma unroll
        for (int m = 0; m < 4; ++m) {
            const int dy = dyr - m;
            if (dy >= 0 && dy < 3) {
                acc[m] = __builtin_amdgcn_mfma_i32_32x32x32_i8(wfr[dy * 3 + 0], bf0, acc[m], 0, 0, 0);
                acc[m] = __builtin_amdgcn_mfma_i32_32x32x32_i8(wfr[dy * 3 + 1], bf1, acc[m], 0, 0, 0);
                acc[m] = __builtin_amdgcn_mfma_i32_32x32x32_i8(wfr[dy * 3 + 2], bf2, acc[m], 0, 0, 0);
            }
        }
    }

#pragma unroll
    for (int m = 0; m < 4; ++m) {
        const int r  = r0 + m;
        const int gy = oy + r;
        int k1 = 0;
#pragma unroll
        for (int dy = 0; dy < 3; ++dy)
#pragma unroll
            for (int dx = 0; dx < 3; ++dx)
                k1 += (int)cs2s[(r + dy) * 34 + (c + dx)];
        const int rc = (gy == 0) ? 0 : ((gy == 191) ? 2 : 1);
        const int cls = rc * 3 + cc;
        const float t2 = C2 * (float)k1;
#pragma unroll
        for (int reg = 0; reg < 16; ++reg) {
            const int co = (reg & 3) + 8 * (reg >> 2) + 4 * ch;
            const float y = fmaf(C1, (float)acc[m][reg], t2 + tlds[cls * 32 + co]);
            out[(((size_t)n * 32 + co) * 192 + gy) * 192 + gx] = y;
        }
    }
}

// ===================== Cooperative mega-kernel =====================
__global__ __launch_bounds__(256, 4) void kMega(
    const float* __restrict__ x, const float* __restrict__ w,
    const float* __restrict__ bias, const int* __restrict__ bits,
    float* __restrict__ partials, unsigned int* __restrict__ wq8,
    int* __restrict__ colJ, float* __restrict__ wstats,
    unsigned int* __restrict__ codes, float* __restrict__ out)
{
    __shared__ __align__(16) char smem[32032];
    const int tid = threadIdx.x;
    cg::grid_group grid = cg::this_grid();

    for (int u = blockIdx.x; u < 2331; u += gridDim.x)
        phaseA_unit(u, tid, x, w, partials, wq8, colJ, wstats, smem);
    __threadfence();
    grid.sync();

    for (int u = blockIdx.x; u < 2304; u += gridDim.x)
        phaseQ_unit(u, tid, x, bits, partials, codes, smem);
    __threadfence();
    grid.sync();

    for (int t = blockIdx.x; t < 2304; t += gridDim.x)
        phaseC_tile(t, tid, codes, bits, partials, colJ, wstats, bias, wq8, out, smem);
}

// ===================== Non-cooperative wrappers (fallback, same phase code) =====================
__global__ __launch_bounds__(256) void kPhaseA(
    const float* __restrict__ x, const float* __restrict__ w,
    float* __restrict__ partials, unsigned int* __restrict__ wq8,
    int* __restrict__ colJ, float* __restrict__ wstats)
{
    __shared__ __align__(16) char smem[3080];
    if (blockIdx.x < 2331) phaseA_unit(blockIdx.x, threadIdx.x, x, w, partials, wq8, colJ, wstats, smem);
}

__global__ __launch_bounds__(256) void kPhaseQ(
    const float* __restrict__ x, const int* __restrict__ bits,
    const float* __restrict__ partials, unsigned int* __restrict__ codes)
{
    __shared__ __align__(16) char smem[264];
    if (blockIdx.x < 2304) phaseQ_unit(blockIdx.x, threadIdx.x, x, bits, partials, codes, smem);
}

__global__ __launch_bounds__(256, 4) void kPhaseC(
    const unsigned int* __restrict__ codes, const int* __restrict__ bits,
    const float* __restrict__ partials, const int* __restrict__ colJ,
    const float* __restrict__ wstats, const float* __restrict__ bias,
    const unsigned int* __restrict__ wq8, float* __restrict__ out)
{
    __shared__ __align__(16) char smem[32032];
    if (blockIdx.x < 2304) phaseC_tile(blockIdx.x, threadIdx.x, codes, bits, partials, colJ, wstats, bias, wq8, out, smem);
}

// ===================== Legacy small-ws fallback (r9 proven, 36-chunk partials) =====================
__global__ __launch_bounds__(256) void kAW_legacy(
    const float* __restrict__ x, const float* __restrict__ w,
    float* __restrict__ partials, unsigned int* __restrict__ wq8,
    int* __restrict__ colJ, float* __restrict__ wstats)
{
    __shared__ float smn[256], smx[256];
    __shared__ int   jred[256];
    __shared__ float s_wmn, s_wmx;
    const int tid = threadIdx.x;

    if (blockIdx.x < 1152) {
        const int batch = blockIdx.x / 36;
        const int blk   = blockIdx.x % 36;
        const float* xb = x + (size_t)batch * 1179648 + (size_t)blk * 32768;
        float mn = INFINITY, mx = -INFINITY;
#pragma unroll
        for (int i = 0; i < 32; ++i) {
            const float4 v = reinterpret_cast<const float4*>(xb)[i * 256 + tid];
            mn = fminf(mn, fminf(fminf(v.x, v.y), fminf(v.z, v.w)));
            mx = fmaxf(mx, fmaxf(fmaxf(v.x, v.y), fmaxf(v.z, v.w)));
        }
        smn[tid] = mn; smx[tid] = mx;
        __syncthreads();
        for (int s = 128; s > 0; s >>= 1) {
            if (tid < s) {
                smn[tid] = fminf(smn[tid], smn[tid + s]);
                smx[tid] = fmaxf(smx[tid], smx[tid + s]);
            }
            __syncthreads();
        }
        if (tid == 0) {
            partials[blockIdx.x * 2 + 0] = smn[0];
            partials[blockIdx.x * 2 + 1] = smx[0];
        }
        return;
    }

    const int wb  = blockIdx.x - 1152;
    const int g   = wb / 9;
    const int tap = wb % 9;

    float wmn = INFINITY, wmx = -INFINITY;
    for (int i = tid; i < 9216; i += 256) {
        const float v = w[i];
        wmn = fminf(wmn, v); wmx = fmaxf(wmx, v);
    }
    smn[tid] = wmn; smx[tid] = wmx; __syncthreads();
    for (int s = 128; s > 0; s >>= 1) {
        if (tid < s) {
            smn[tid] = fminf(smn[tid], smn[tid + s]);
            smx[tid] = fmaxf(smx[tid], smx[tid + s]);
        }
        __syncthreads();
    }
    if (tid == 0) { s_wmn = smn[0]; s_wmx = smx[0]; }
    __syncthreads();
    if (wb == 0 && tid == 0) { wstats[0] = s_wmn; wstats[1] = s_wmx; }

    const float wmv = s_wmn, wxv = s_wmx;
    const int bval = 2 << g;
    const float denom = (float)((1 << bval) - 1);
    const float t = fmaxf((wxv - wmv) / denom, EPSQ);
    const int sig = 1 << (bval - 1);

    const int co = tid & 31;
    const int q  = tid >> 5;
    unsigned int packed = 0;
    int jsum = 0;
#pragma unroll
    for (int b = 0; b < 4; ++b) {
        const int ci = q * 4 + b;
        int jc = (int)rintf((w[co * 288 + ci * 9 + tap] - wmv) / t) - sig;
        jc = jc < -128 ? -128 : (jc > 127 ? 127 : jc);
        jsum += jc;
        packed |= ((unsigned int)(unsigned char)(char)jc) << (8 * b);
    }
    const int lane_ = (q >> 2) * 32 + co;
    const int a4    = q & 3;
    wq8[((size_t)(g * 9 + tap) * 64 + lane_) * 4 + a4] = packed;

    jred[tid] = jsum; __syncthreads();
    if (tid < 128) jred[tid] += jred[tid + 128];
    __syncthreads();
    if (tid < 64) jred[tid] += jred[tid + 64];
    __syncthreads();
    if (tid < 32) colJ[g * 288 + tap * 32 + tid] = jred[tid] + jred[tid + 32];
}

__global__ __launch_bounds__(256) void kB2_stats_tbl(
    const float* __restrict__ bias, const int* __restrict__ bits,
    const float* __restrict__ partials, const int* __restrict__ colJ,
    const float* __restrict__ wstats,
    float* __restrict__ gstats, float* __restrict__ coefs, float* __restrict__ tbl)
{
    __shared__ float bmn[32], bmx[32];
    __shared__ float s_gmn[3], s_gs[3];
    const int tid = threadIdx.x;
    const float wmv = wstats[0], wxv = wstats[1];

    if (tid < 32) {
        float mn = INFINITY, mx = -INFINITY;
        for (int i = 0; i < 36; ++i) {
            mn = fminf(mn, partials[(tid * 36 + i) * 2 + 0]);
            mx = fmaxf(mx, partials[(tid * 36 + i) * 2 + 1]);
        }
        bmn[tid] = mn; bmx[tid] = mx;
    }
    __syncthreads();

    if (tid < 3) {
        const int bval = 2 << tid;
        const float denom = (float)((1 << bval) - 1);
        float mn = INFINITY, mx = -INFINITY; bool has = false;
        for (int nb = 0; nb < 32; ++nb) {
            if (bits[nb] == bval) { has = true; mn = fminf(mn, bmn[nb]); mx = fmaxf(mx, bmx[nb]); }
        }
        if (!has) { mn = 0.f; mx = 0.f; }
        const float scale = fmaxf((mx - mn) / denom, EPSQ);
        gstats[tid * 2 + 0] = mn;
        gstats[tid * 2 + 1] = scale;
        s_gmn[tid] = mn; s_gs[tid] = scale;

        const float t = fmaxf((wxv - wmv) / denom, EPSQ);
        const int sig = 1 << (bval - 1);
        const double B_ = (double)wmv + (double)sig * (double)t;
        coefs[tid * 2 + 0] = (float)((double)scale * (double)t);
        coefs[tid * 2 + 1] = (float)((double)scale * B_);
    }
    __syncthreads();

    for (int idx = tid; idx < 864; idx += 256) {
        const int g   = idx / 288;
        const int rem = idx % 288;
        const int cls = rem / 32;
        const int co  = rem % 32;
        const int bval = 2 << g;
        const float denom = (float)((1 << bval) - 1);
        const float t = fmaxf((wxv - wmv) / denom, EPSQ);
        const int sig = 1 << (bval - 1);
        const double A_ = (double)s_gmn[g] + (double)sig * (double)s_gs[g];
        const double B_ = (double)wmv + (double)sig * (double)t;
        const int rc = cls / 3, cc = cls % 3;
        double js = 0.0, ij = 0.0; int ninv = 0;
        for (int tap = 0; tap < 9; ++tap) {
            const int dy = tap / 3, dx = tap % 3;
            const int cj = colJ[g * 288 + tap * 32 + co];
            js += (double)cj;
            const bool inv = (rc == 0 && dy == 0) || (rc == 2 && dy == 2) ||
                             (cc == 0 && dx == 0) || (cc == 2 && dx == 2);
            if (inv) { ++ninv; ij += (double)cj; }
        }
        const double v = (double)t * A_ * js + 288.0 * A_ * B_ + (double)bias[co]
                       - A_ * (32.0 * B_ * (double)ninv + (double)t * ij);
        tbl[idx] = (float)v;
    }
}

__global__ __launch_bounds__(256, 4) void kC_fused(
    const float* __restrict__ x, const int* __restrict__ bits,
    const float* __restrict__ gstats, const float* __restrict__ coefs,
    const float* __restrict__ tbl, const unsigned int* __restrict__ wq8,
    float* __restrict__ out)
{
    __shared__ v4i   xkv[18 * 34 * 3];
    __shared__ short cs2s[18 * 34];
    __shared__ float tlds[288];

    const int n  = blockIdx.z;
    const int oy = blockIdx.y * 16;
    const int ox = blockIdx.x * 32;
    const int tid  = threadIdx.x;
    const int lane = tid & 63;
    const int wv   = tid >> 6;

    const int bval = bits[n];
    const int g = (bval == 2) ? 0 : (bval == 4 ? 1 : 2);
    const int sig = 1 << (bval - 1);
    const float mn = gstats[g * 2 + 0];
    const float s  = gstats[g * 2 + 1];
    const float C1 = coefs[g * 2 + 0];
    const float C2 = coefs[g * 2 + 1];

    const v4i* wA = (const v4i*)(wq8 + (size_t)g * 2304);
    v4i wfr[9];
#pragma unroll
    for (int t = 0; t < 9; ++t) wfr[t] = wA[t * 64 + lane];

    for (int i = tid; i < 288; i += 256) tlds[i] = tbl[g * 288 + i];

    const float* xn = x + (size_t)n * 1179648;
    char* xk = (char*)xkv;
    for (int px = tid; px < 612; px += 256) {
        const int r = px / 34;
        const int c = px - r * 34;
        const int gy = oy + r - 1, gx = ox + c - 1;
        const bool valid = ((unsigned)gy < 192u) && ((unsigned)gx < 192u);
        const float* xp = xn + (size_t)(valid ? gy : 0) * 192 + (valid ? gx : 0);
        int ksum = 0;
        v4i pk0, pk1;
#pragma unroll
        for (int h = 0; h < 2; ++h) {
            float v[16];
#pragma unroll
            for (int i = 0; i < 16; ++i) v[i] = xp[(size_t)(h * 16 + i) * 36864];
            int w4[4];
#pragma unroll
            for (int q4 = 0; q4 < 4; ++q4) {
                unsigned int pw = 0;
#pragma unroll
                for (int b = 0; b < 4; ++b) {
                    int kq = (int)rintf((v[q4 * 4 + b] - mn) / s) - sig;
                    kq = kq < -128 ? -128 : (kq > 127 ? 127 : kq);
                    ksum += kq;
                    pw |= ((unsigned int)(unsigned char)(char)kq) << (8 * b);
                }
                w4[q4] = (int)pw;
            }
            if (h == 0) pk0 = (v4i){w4[0], w4[1], w4[2], w4[3]};
            else        pk1 = (v4i){w4[0], w4[1], w4[2], w4[3]};
        }
        if (!valid) { pk0 = (v4i){0,0,0,0}; pk1 = (v4i){0,0,0,0}; ksum = 0; }
        *(v4i*)(xk + px * 48 +  0) = pk0;
        *(v4i*)(xk + px * 48 + 16) = pk1;
        cs2s[px] = (short)ksum;
    }
    __syncthreads();

    const int c  = lane & 31;
    const int ch = lane >> 5;
    const int gx = ox + c;
    const int cc = (gx == 0) ? 0 : ((gx == 191) ? 2 : 1);
    const int r0 = wv * 4;

    v16i acc[4] = {};
#pragma unroll
    for (int dyr = 0; dyr < 6; ++dyr) {
        const int xrow = r0 + dyr;
        const v4i bf0 = xkv[(xrow * 34 + c + 0) * 3 + ch];
        const v4i bf1 = xkv[(xrow * 34 + c + 1) * 3 + ch];
        const v4i bf2 = xkv[(xrow * 34 + c + 2) * 3 + ch];
#pragma unroll
        for (int m = 0; m < 4; ++m) {
            const int dy = dyr - m;
            if (dy >= 0 && dy < 3) {
                acc[m] = __builtin_amdgcn_mfma_i32_32x32x32_i8(wfr[dy * 3 + 0], bf0, acc[m], 0, 0, 0);
                acc[m] = __builtin_amdgcn_mfma_i32_32x32x32_i8(wfr[dy * 3 + 1], bf1, acc[m], 0, 0, 0);
                acc[m] = __builtin_amdgcn_mfma_i32_32x32x32_i8(wfr[dy * 3 + 2], bf2, acc[m], 0, 0, 0);
            }
        }
    }

#pragma unroll
    for (int m = 0; m < 4; ++m) {
        const int r  = r0 + m;
        const int gy = oy + r;
        int k1 = 0;
#pragma unroll
        for (int dy = 0; dy < 3; ++dy)
#pragma unroll
            for (int dx = 0; dx < 3; ++dx)
                k1 += (int)cs2s[(r + dy) * 34 + (c + dx)];
        const int rc = (gy == 0) ? 0 : ((gy == 191) ? 2 : 1);
        const int cls = rc * 3 + cc;
        const float t2 = C2 * (float)k1;
#pragma unroll
        for (int reg = 0; reg < 16; ++reg) {
            const int co = (reg & 3) + 8 * (reg >> 2) + 4 * ch;
            const float y = fmaf(C1, (float)acc[m][reg], t2 + tlds[cls * 32 + co]);
            out[(((size_t)n * 32 + co) * 192 + gy) * 192 + gx] = y;
        }
    }
}

extern "C" void kernel_launch(void* const* d_in, const int* in_sizes, int n_in,
                              void* d_out, int out_size, void* d_ws, size_t ws_size,
                              hipStream_t stream) {
    const float* x      = (const float*)d_in[0];
    const float* weight = (const float*)d_in[1];
    const float* bias   = (const float*)d_in[2];
    const int*   bits   = (const int*)d_in[3];
    float* out = (float*)d_out;

    float* ws = (float*)d_ws;
    // --- coop/3-launch layout (72 chunks/batch) ---
    float* partials = ws;                            // 4608 floats
    int*   colJ     = (int*)(ws + 4608);             // 864 ints
    unsigned int* wq8 = (unsigned int*)(ws + 5472);  // 6912 u32
    float* wstats   = ws + 12384;                    // 2 floats
    // --- legacy layout (only used if !big_ws) ---
    float* lpart    = ws + 12416;                    // 2304 floats
    float* gstats   = ws + 14720;                    // 8
    float* coefs    = ws + 14728;                    // 8
    float* tbl      = ws + 14736;                    // 864 -> ends 15600
    const size_t codes_off   = 62464;                // 64B-aligned byte offset
    const size_t codes_bytes = 37748736ull;
    unsigned int* codes = (unsigned int*)((char*)d_ws + codes_off);
    const bool big_ws = ws_size >= codes_off + codes_bytes;

    if (big_ws) {
        const int coopGrid = 777;                    // 3 balanced iterations per phase
        int maxPerCU = 0;
        hipError_t qe = hipOccupancyMaxActiveBlocksPerMultiprocessor(&maxPerCU, kMega, 256, 0);
        int coopAttr = 0;
        int dev = 0;
        hipGetDevice(&dev);
        hipDeviceGetAttribute(&coopAttr, hipDeviceAttributeCooperativeLaunch, dev);

        if (qe == hipSuccess && coopAttr && (size_t)maxPerCU * 256 >= (size_t)coopGrid) {
            void* args[] = {(void*)&x, (void*)&weight, (void*)&bias, (void*)&bits,
                            (void*)&partials, (void*)&wq8, (void*)&colJ, (void*)&wstats,
                            (void*)&codes, (void*)&out};
            hipError_t le = hipLaunchCooperativeKernel(kMega, dim3(coopGrid), dim3(256),
                                                       args, 0, stream);
            if (le == hipSuccess) return;
        }
        // non-cooperative fallback: same phases, 3 launches
        kPhaseA<<<2331, 256, 0, stream>>>(x, weight, partials, wq8, colJ, wstats);
        kPhaseQ<<<2304, 256, 0, stream>>>(x, bits, partials, codes);
        kPhaseC<<<2304, 256, 0, stream>>>(codes, bits, partials, colJ, wstats, bias, wq8, out);
        return;
    }

    // legacy small-ws path (r9 proven)
    kAW_legacy<<<1179, 256, 0, stream>>>(x, weight, lpart, wq8, colJ, wstats);
    kB2_stats_tbl<<<1, 256, 0, stream>>>(bias, bits, lpart, colJ, wstats, gstats, coefs, tbl);
    dim3 grid(6, 12, 32);
    kC_fused<<<grid, 256, 0, stream>>>(x, bits, gstats, coefs, tbl, wq8, out);
}

// Round 11
// 110.369 us; speedup vs baseline: 1.2142x; 1.2142x over previous
//
#include <hip/hip_runtime.h>

#define EPSQ 1e-8f

typedef int v4i  __attribute__((ext_vector_type(4)));
typedef int v16i __attribute__((ext_vector_type(16)));

// x: (32, 32, 192, 192) f32; weight: (32, 32, 3, 3) f32; bias: (32,) f32; bits: (32,) i32
//
// Integer-exact decomposition (per batch n with group g, σ=2^(b-1)):
//   x_q = mn + s·k,  w_q = wm + t·j,  kc = k−σ, jc = j−σ  (i8, centered)
//   y[p,co] = s·t·KJ[p,co] + s·(wm+σt)·K1[p] + Tbl[class(p)][co]
//   KJ = Σ_{taps,ci} kc·jc  (i8 MFMA, exact i32; pad kc=0)
//   K1 = Σ_{taps,ci} kc     (box sum of per-pixel ci-sums; pad 0)
// k and j use the same IEEE f32 div + rintf as the reference → identical quant decisions.
//
// r11 = r9 structure (3 launches, proven 118.6) + kC de-fattening:
//   - coefs+Tbl computed once in kQ block 0 (exact kB2 math) instead of per kC block
//   - kC epilogue k1 via 6 row-sums (18 LDS reads, was 36)
//   - nontemporal out stores (out never re-read; keep codes cache-resident)

__device__ __forceinline__ int bytesum4(int v) {
#if __has_builtin(__builtin_amdgcn_sdot4)
    return __builtin_amdgcn_sdot4(v, 0x01010101, 0, false);
#else
    return (int)(char)(v) + (int)(char)(v >> 8) + (int)(char)(v >> 16) + (int)(char)(v >> 24);
#endif
}

// ---------------- Kernel AW: x min/max partials (blocks 0..1151) + weight codes (1152..1178) ----------------
__global__ __launch_bounds__(256) void kAW(
    const float* __restrict__ x, const float* __restrict__ w,
    float* __restrict__ partials, unsigned int* __restrict__ wq8,
    int* __restrict__ colJ, float* __restrict__ wstats)
{
    __shared__ float smn[256], smx[256];
    __shared__ int   jred[256];
    __shared__ float s_wmn, s_wmx;
    const int tid = threadIdx.x;

    if (blockIdx.x < 1152) {
        const int batch = blockIdx.x / 36;
        const int blk   = blockIdx.x % 36;
        const float* xb = x + (size_t)batch * 1179648 + (size_t)blk * 32768;
        float mn = INFINITY, mx = -INFINITY;
#pragma unroll
        for (int i = 0; i < 32; ++i) {
            const float4 v = reinterpret_cast<const float4*>(xb)[i * 256 + tid];
            mn = fminf(mn, fminf(fminf(v.x, v.y), fminf(v.z, v.w)));
            mx = fmaxf(mx, fmaxf(fmaxf(v.x, v.y), fmaxf(v.z, v.w)));
        }
        smn[tid] = mn; smx[tid] = mx;
        __syncthreads();
        for (int s = 128; s > 0; s >>= 1) {
            if (tid < s) {
                smn[tid] = fminf(smn[tid], smn[tid + s]);
                smx[tid] = fmaxf(smx[tid], smx[tid + s]);
            }
            __syncthreads();
        }
        if (tid == 0) {
            partials[blockIdx.x * 2 + 0] = smn[0];
            partials[blockIdx.x * 2 + 1] = smx[0];
        }
        return;
    }

    const int wb  = blockIdx.x - 1152;
    const int g   = wb / 9;
    const int tap = wb % 9;

    float wmn = INFINITY, wmx = -INFINITY;
    for (int i = tid; i < 9216; i += 256) {
        const float v = w[i];
        wmn = fminf(wmn, v); wmx = fmaxf(wmx, v);
    }
    smn[tid] = wmn; smx[tid] = wmx; __syncthreads();
    for (int s = 128; s > 0; s >>= 1) {
        if (tid < s) {
            smn[tid] = fminf(smn[tid], smn[tid + s]);
            smx[tid] = fmaxf(smx[tid], smx[tid + s]);
        }
        __syncthreads();
    }
    if (tid == 0) { s_wmn = smn[0]; s_wmx = smx[0]; }
    __syncthreads();
    if (wb == 0 && tid == 0) { wstats[0] = s_wmn; wstats[1] = s_wmx; }

    const float wmv = s_wmn, wxv = s_wmx;
    const int bval = 2 << g;
    const float denom = (float)((1 << bval) - 1);
    const float t = fmaxf((wxv - wmv) / denom, EPSQ);
    const int sig = 1 << (bval - 1);

    const int co = tid & 31;
    const int q  = tid >> 5;
    unsigned int packed = 0;
    int jsum = 0;
#pragma unroll
    for (int b = 0; b < 4; ++b) {
        const int ci = q * 4 + b;
        int jc = (int)rintf((w[co * 288 + ci * 9 + tap] - wmv) / t) - sig;  // IEEE div, as ref
        jc = jc < -128 ? -128 : (jc > 127 ? 127 : jc);
        jsum += jc;
        packed |= ((unsigned int)(unsigned char)(char)jc) << (8 * b);
    }
    const int lane_ = (q >> 2) * 32 + co;
    const int a4    = q & 3;
    wq8[((size_t)(g * 9 + tap) * 64 + lane_) * 4 + a4] = packed;

    jred[tid] = jsum; __syncthreads();
    if (tid < 128) jred[tid] += jred[tid + 128];
    __syncthreads();
    if (tid < 64) jred[tid] += jred[tid + 64];
    __syncthreads();
    if (tid < 32) colJ[g * 288 + tap * 32 + tid] = jred[tid] + jred[tid + 32];
}

// ---------------- Kernel Q: quantize x to channel-last i8 codes; block 0 also emits coefs+Tbl ----------------
__global__ __launch_bounds__(256) void kQ_quant(
    const float* __restrict__ x, const int* __restrict__ bits,
    const float* __restrict__ partials, const int* __restrict__ colJ,
    const float* __restrict__ wstats, const float* __restrict__ bias,
    unsigned int* __restrict__ codes,
    float* __restrict__ coefs, float* __restrict__ tbl)
{
    __shared__ float bmn[32], bmx[32];
    __shared__ float s_mn, s_sc;
    __shared__ float s_gmn[3], s_gs[3];

    const int n     = blockIdx.x / 36;
    const int chunk = blockIdx.x % 36;
    const int tid   = threadIdx.x;
    const int bval  = bits[n];
    const int sig   = 1 << (bval - 1);

    if (tid < 32) {
        float mn = INFINITY, mx = -INFINITY;
        for (int i = 0; i < 36; ++i) {
            mn = fminf(mn, partials[(tid * 36 + i) * 2 + 0]);
            mx = fmaxf(mx, partials[(tid * 36 + i) * 2 + 1]);
        }
        bmn[tid] = mn; bmx[tid] = mx;
    }
    __syncthreads();
    if (tid == 0) {
        float mn = INFINITY, mx = -INFINITY;
        for (int nb = 0; nb < 32; ++nb)
            if (bits[nb] == bval) { mn = fminf(mn, bmn[nb]); mx = fmaxf(mx, bmx[nb]); }
        const float denom = (float)((1 << bval) - 1);
        s_mn = mn;
        s_sc = fmaxf((mx - mn) / denom, EPSQ);
    }
    __syncthreads();
    const float mn = s_mn, s = s_sc;

    // ---- block 0: coefs + Tbl for all 3 groups (exact kB2 math/order) ----
    if (blockIdx.x == 0) {
        const float wmv = wstats[0], wxv = wstats[1];
        if (tid < 3) {
            const int bv = 2 << tid;
            const float denom = (float)((1 << bv) - 1);
            float gmn = INFINITY, gmx = -INFINITY; bool has = false;
            for (int nb = 0; nb < 32; ++nb) {
                if (bits[nb] == bv) { has = true; gmn = fminf(gmn, bmn[nb]); gmx = fmaxf(gmx, bmx[nb]); }
            }
            if (!has) { gmn = 0.f; gmx = 0.f; }
            const float scale = fmaxf((gmx - gmn) / denom, EPSQ);
            s_gmn[tid] = gmn; s_gs[tid] = scale;

            const float t = fmaxf((wxv - wmv) / denom, EPSQ);
            const int sg = 1 << (bv - 1);
            const double B_ = (double)wmv + (double)sg * (double)t;
            coefs[tid * 2 + 0] = (float)((double)scale * (double)t);
            coefs[tid * 2 + 1] = (float)((double)scale * B_);
        }
        __syncthreads();
        for (int idx = tid; idx < 864; idx += 256) {
            const int g   = idx / 288;
            const int rem = idx % 288;
            const int cls = rem / 32;
            const int co  = rem % 32;
            const int bv = 2 << g;
            const float denom = (float)((1 << bv) - 1);
            const float t = fmaxf((wxv - wmv) / denom, EPSQ);
            const int sg = 1 << (bv - 1);
            const double A_ = (double)s_gmn[g] + (double)sg * (double)s_gs[g];
            const double B_ = (double)wmv + (double)sg * (double)t;
            const int rc = cls / 3, cc = cls % 3;
            double js = 0.0, ij = 0.0; int ninv = 0;
            for (int tap = 0; tap < 9; ++tap) {
                const int dy = tap / 3, dx = tap % 3;
                const int cj = colJ[g * 288 + tap * 32 + co];
                js += (double)cj;
                const bool inv = (rc == 0 && dy == 0) || (rc == 2 && dy == 2) ||
                                 (cc == 0 && dx == 0) || (cc == 2 && dx == 2);
                if (inv) { ++ninv; ij += (double)cj; }
            }
            const double v = (double)t * A_ * js + 288.0 * A_ * B_ + (double)bias[co]
                           - A_ * (32.0 * B_ * (double)ninv + (double)t * ij);
            tbl[idx] = (float)v;
        }
    }

    // ---- quantize 4 px x 32 ci per thread ----
    const int px0 = chunk * 1024 + tid * 4;
    const float* xn = x + (size_t)n * 1179648;

    unsigned int creg[32];
#pragma unroll
    for (int i = 0; i < 32; ++i) creg[i] = 0;

#pragma unroll
    for (int ci = 0; ci < 32; ++ci) {
        const float4 v = *(const float4*)(xn + (size_t)ci * 36864 + px0);
        const float vv[4] = {v.x, v.y, v.z, v.w};
#pragma unroll
        for (int p = 0; p < 4; ++p) {
            // IEEE f32 div + rintf: identical quant decisions to reference
            int kq = (int)rintf((vv[p] - mn) / s) - sig;
            kq = kq < -128 ? -128 : (kq > 127 ? 127 : kq);
            creg[p * 8 + (ci >> 2)] |= ((unsigned int)(unsigned char)(char)kq) << (8 * (ci & 3));
        }
    }

    unsigned int* cp = codes + ((size_t)n * 36864 + (size_t)px0) * 8;
#pragma unroll
    for (int p = 0; p < 4; ++p) {
        *(v4i*)(cp + p * 8 + 0) = (v4i){(int)creg[p*8+0], (int)creg[p*8+1], (int)creg[p*8+2], (int)creg[p*8+3]};
        *(v4i*)(cp + p * 8 + 4) = (v4i){(int)creg[p*8+4], (int)creg[p*8+5], (int)creg[p*8+6], (int)creg[p*8+7]};
    }
}

// ---------------- Kernel C: i8-MFMA conv (lean: loads coefs+tbl) ----------------
// grid = (6, 12, 32); block 256 (4 waves). Tile 16 rows x 32 cols, all 32 co.
__global__ __launch_bounds__(256, 4) void kC_codes(
    const unsigned int* __restrict__ codes, const int* __restrict__ bits,
    const float* __restrict__ coefs, const float* __restrict__ tbl,
    const unsigned int* __restrict__ wq8, float* __restrict__ out)
{
    __shared__ v4i   xkv[18 * 34 * 3];   // centered i8 codes [px][48B pitch]
    __shared__ short cs2s[18 * 34];
    __shared__ float tlds[288];

    const int n  = blockIdx.z;
    const int oy = blockIdx.y * 16;
    const int ox = blockIdx.x * 32;
    const int tid  = threadIdx.x;
    const int lane = tid & 63;
    const int wv   = tid >> 6;

    const int bval = bits[n];
    const int g = (bval == 2) ? 0 : (bval == 4 ? 1 : 2);
    const float C1 = coefs[g * 2 + 0];
    const float C2 = coefs[g * 2 + 1];

    const v4i* wA = (const v4i*)(wq8 + (size_t)g * 2304);
    v4i wfr[9];
#pragma unroll
    for (int t = 0; t < 9; ++t) wfr[t] = wA[t * 64 + lane];

    for (int i = tid; i < 288; i += 256) tlds[i] = tbl[g * 288 + i];

    // ---- stage codes (pad -> 0) ----
    const unsigned int* cb = codes + (size_t)n * 36864 * 8;
    char* xk = (char*)xkv;
    for (int px = tid; px < 612; px += 256) {
        const int r = px / 34;
        const int c = px - r * 34;
        const int gy = oy + r - 1, gx = ox + c - 1;
        v4i pk0 = (v4i){0,0,0,0}, pk1 = (v4i){0,0,0,0};
        int ksum = 0;
        if (((unsigned)gy < 192u) && ((unsigned)gx < 192u)) {
            const unsigned int* p = cb + ((size_t)gy * 192 + gx) * 8;
            pk0 = *(const v4i*)(p + 0);
            pk1 = *(const v4i*)(p + 4);
            ksum = bytesum4(pk0.x) + bytesum4(pk0.y) + bytesum4(pk0.z) + bytesum4(pk0.w)
                 + bytesum4(pk1.x) + bytesum4(pk1.y) + bytesum4(pk1.z) + bytesum4(pk1.w);
        }
        *(v4i*)(xk + px * 48 +  0) = pk0;
        *(v4i*)(xk + px * 48 + 16) = pk1;
        cs2s[px] = (short)ksum;
    }
    __syncthreads();

    // ---- MFMA conv + epilogue (one 4-row quad per wave) ----
    const int c  = lane & 31;
    const int ch = lane >> 5;
    const int gx = ox + c;
    const int cc = (gx == 0) ? 0 : ((gx == 191) ? 2 : 1);
    const int r0 = wv * 4;

    v16i acc[4] = {};
#pragma unroll
    for (int dyr = 0; dyr < 6; ++dyr) {
        const int xrow = r0 + dyr;
        const v4i bf0 = xkv[(xrow * 34 + c + 0) * 3 + ch];
        const v4i bf1 = xkv[(xrow * 34 + c + 1) * 3 + ch];
        const v4i bf2 = xkv[(xrow * 34 + c + 2) * 3 + ch];
#pragma unroll
        for (int m = 0; m < 4; ++m) {
            const int dy = dyr - m;
            if (dy >= 0 && dy < 3) {
                acc[m] = __builtin_amdgcn_mfma_i32_32x32x32_i8(wfr[dy * 3 + 0], bf0, acc[m], 0, 0, 0);
                acc[m] = __builtin_amdgcn_mfma_i32_32x32x32_i8(wfr[dy * 3 + 1], bf1, acc[m], 0, 0, 0);
                acc[m] = __builtin_amdgcn_mfma_i32_32x32x32_i8(wfr[dy * 3 + 2], bf2, acc[m], 0, 0, 0);
            }
        }
    }

    // row-sums of cs2s over the 3-col window: 18 LDS reads (was 36); int adds = exact
    int rs[6];
#pragma unroll
    for (int dy = 0; dy < 6; ++dy) {
        const int row = r0 + dy;
        rs[dy] = (int)cs2s[row * 34 + c] + (int)cs2s[row * 34 + c + 1] + (int)cs2s[row * 34 + c + 2];
    }

#pragma unroll
    for (int m = 0; m < 4; ++m) {
        const int gy = oy + r0 + m;
        const int k1 = rs[m] + rs[m + 1] + rs[m + 2];
        const int rc = (gy == 0) ? 0 : ((gy == 191) ? 2 : 1);
        const int cls = rc * 3 + cc;
        const float t2 = C2 * (float)k1;
#pragma unroll
        for (int reg = 0; reg < 16; ++reg) {
            const int co = (reg & 3) + 8 * (reg >> 2) + 4 * ch;
            const float y = fmaf(C1, (float)acc[m][reg], t2 + tlds[cls * 32 + co]);
            __builtin_nontemporal_store(y, &out[(((size_t)n * 32 + co) * 192 + gy) * 192 + gx]);
        }
    }
}

// ---------------- Fallback path (small ws): kB2 + fused conv (r7/r8/r9 proven) ----------------
__global__ __launch_bounds__(256) void kB2_stats_tbl(
    const float* __restrict__ bias, const int* __restrict__ bits,
    const float* __restrict__ partials, const int* __restrict__ colJ,
    const float* __restrict__ wstats,
    float* __restrict__ gstats, float* __restrict__ coefs, float* __restrict__ tbl)
{
    __shared__ float bmn[32], bmx[32];
    __shared__ float s_gmn[3], s_gs[3];
    const int tid = threadIdx.x;
    const float wmv = wstats[0], wxv = wstats[1];

    if (tid < 32) {
        float mn = INFINITY, mx = -INFINITY;
        for (int i = 0; i < 36; ++i) {
            mn = fminf(mn, partials[(tid * 36 + i) * 2 + 0]);
            mx = fmaxf(mx, partials[(tid * 36 + i) * 2 + 1]);
        }
        bmn[tid] = mn; bmx[tid] = mx;
    }
    __syncthreads();

    if (tid < 3) {
        const int bval = 2 << tid;
        const float denom = (float)((1 << bval) - 1);
        float mn = INFINITY, mx = -INFINITY; bool has = false;
        for (int nb = 0; nb < 32; ++nb) {
            if (bits[nb] == bval) { has = true; mn = fminf(mn, bmn[nb]); mx = fmaxf(mx, bmx[nb]); }
        }
        if (!has) { mn = 0.f; mx = 0.f; }
        const float scale = fmaxf((mx - mn) / denom, EPSQ);
        gstats[tid * 2 + 0] = mn;
        gstats[tid * 2 + 1] = scale;
        s_gmn[tid] = mn; s_gs[tid] = scale;

        const float t = fmaxf((wxv - wmv) / denom, EPSQ);
        const int sig = 1 << (bval - 1);
        const double B_ = (double)wmv + (double)sig * (double)t;
        coefs[tid * 2 + 0] = (float)((double)scale * (double)t);
        coefs[tid * 2 + 1] = (float)((double)scale * B_);
    }
    __syncthreads();

    for (int idx = tid; idx < 864; idx += 256) {
        const int g   = idx / 288;
        const int rem = idx % 288;
        const int cls = rem / 32;
        const int co  = rem % 32;
        const int bval = 2 << g;
        const float denom = (float)((1 << bval) - 1);
        const float t = fmaxf((wxv - wmv) / denom, EPSQ);
        const int sig = 1 << (bval - 1);
        const double A_ = (double)s_gmn[g] + (double)sig * (double)s_gs[g];
        const double B_ = (double)wmv + (double)sig * (double)t;
        const int rc = cls / 3, cc = cls % 3;
        double js = 0.0, ij = 0.0; int ninv = 0;
        for (int tap = 0; tap < 9; ++tap) {
            const int dy = tap / 3, dx = tap % 3;
            const int cj = colJ[g * 288 + tap * 32 + co];
            js += (double)cj;
            const bool inv = (rc == 0 && dy == 0) || (rc == 2 && dy == 2) ||
                             (cc == 0 && dx == 0) || (cc == 2 && dx == 2);
            if (inv) { ++ninv; ij += (double)cj; }
        }
        const double v = (double)t * A_ * js + 288.0 * A_ * B_ + (double)bias[co]
                       - A_ * (32.0 * B_ * (double)ninv + (double)t * ij);
        tbl[idx] = (float)v;
    }
}

__global__ __launch_bounds__(256, 4) void kC_fused(
    const float* __restrict__ x, const int* __restrict__ bits,
    const float* __restrict__ gstats, const float* __restrict__ coefs,
    const float* __restrict__ tbl, const unsigned int* __restrict__ wq8,
    float* __restrict__ out)
{
    __shared__ v4i   xkv[18 * 34 * 3];
    __shared__ short cs2s[18 * 34];
    __shared__ float tlds[288];

    const int n  = blockIdx.z;
    const int oy = blockIdx.y * 16;
    const int ox = blockIdx.x * 32;
    const int tid  = threadIdx.x;
    const int lane = tid & 63;
    const int wv   = tid >> 6;

    const int bval = bits[n];
    const int g = (bval == 2) ? 0 : (bval == 4 ? 1 : 2);
    const int sig = 1 << (bval - 1);
    const float mn = gstats[g * 2 + 0];
    const float s  = gstats[g * 2 + 1];
    const float C1 = coefs[g * 2 + 0];
    const float C2 = coefs[g * 2 + 1];

    const v4i* wA = (const v4i*)(wq8 + (size_t)g * 2304);
    v4i wfr[9];
#pragma unroll
    for (int t = 0; t < 9; ++t) wfr[t] = wA[t * 64 + lane];

    for (int i = tid; i < 288; i += 256) tlds[i] = tbl[g * 288 + i];

    const float* xn = x + (size_t)n * 1179648;
    char* xk = (char*)xkv;
    for (int px = tid; px < 612; px += 256) {
        const int r = px / 34;
        const int c = px - r * 34;
        const int gy = oy + r - 1, gx = ox + c - 1;
        const bool valid = ((unsigned)gy < 192u) && ((unsigned)gx < 192u);
        const float* xp = xn + (size_t)(valid ? gy : 0) * 192 + (valid ? gx : 0);
        int ksum = 0;
        v4i pk0, pk1;
#pragma unroll
        for (int h = 0; h < 2; ++h) {
            float v[16];
#pragma unroll
            for (int i = 0; i < 16; ++i) v[i] = xp[(size_t)(h * 16 + i) * 36864];
            int w4[4];
#pragma unroll
            for (int q4 = 0; q4 < 4; ++q4) {
                unsigned int pw = 0;
#pragma unroll
                for (int b = 0; b < 4; ++b) {
                    int kq = (int)rintf((v[q4 * 4 + b] - mn) / s) - sig;
                    kq = kq < -128 ? -128 : (kq > 127 ? 127 : kq);
                    ksum += kq;
                    pw |= ((unsigned int)(unsigned char)(char)kq) << (8 * b);
                }
                w4[q4] = (int)pw;
            }
            if (h == 0) pk0 = (v4i){w4[0], w4[1], w4[2], w4[3]};
            else        pk1 = (v4i){w4[0], w4[1], w4[2], w4[3]};
        }
        if (!valid) { pk0 = (v4i){0,0,0,0}; pk1 = (v4i){0,0,0,0}; ksum = 0; }
        *(v4i*)(xk + px * 48 +  0) = pk0;
        *(v4i*)(xk + px * 48 + 16) = pk1;
        cs2s[px] = (short)ksum;
    }
    __syncthreads();

    const int c  = lane & 31;
    const int ch = lane >> 5;
    const int gx = ox + c;
    const int cc = (gx == 0) ? 0 : ((gx == 191) ? 2 : 1);
    const int r0 = wv * 4;

    v16i acc[4] = {};
#pragma unroll
    for (int dyr = 0; dyr < 6; ++dyr) {
        const int xrow = r0 + dyr;
        const v4i bf0 = xkv[(xrow * 34 + c + 0) * 3 + ch];
        const v4i bf1 = xkv[(xrow * 34 + c + 1) * 3 + ch];
        const v4i bf2 = xkv[(xrow * 34 + c + 2) * 3 + ch];
#pragma unroll
        for (int m = 0; m < 4; ++m) {
            const int dy = dyr - m;
            if (dy >= 0 && dy < 3) {
                acc[m] = __builtin_amdgcn_mfma_i32_32x32x32_i8(wfr[dy * 3 + 0], bf0, acc[m], 0, 0, 0);
                acc[m] = __builtin_amdgcn_mfma_i32_32x32x32_i8(wfr[dy * 3 + 1], bf1, acc[m], 0, 0, 0);
                acc[m] = __builtin_amdgcn_mfma_i32_32x32x32_i8(wfr[dy * 3 + 2], bf2, acc[m], 0, 0, 0);
            }
        }
    }

#pragma unroll
    for (int m = 0; m < 4; ++m) {
        const int r  = r0 + m;
        const int gy = oy + r;
        int k1 = 0;
#pragma unroll
        for (int dy = 0; dy < 3; ++dy)
#pragma unroll
            for (int dx = 0; dx < 3; ++dx)
                k1 += (int)cs2s[(r + dy) * 34 + (c + dx)];
        const int rc = (gy == 0) ? 0 : ((gy == 191) ? 2 : 1);
        const int cls = rc * 3 + cc;
        const float t2 = C2 * (float)k1;
#pragma unroll
        for (int reg = 0; reg < 16; ++reg) {
            const int co = (reg & 3) + 8 * (reg >> 2) + 4 * ch;
            const float y = fmaf(C1, (float)acc[m][reg], t2 + tlds[cls * 32 + co]);
            out[(((size_t)n * 32 + co) * 192 + gy) * 192 + gx] = y;
        }
    }
}

extern "C" void kernel_launch(void* const* d_in, const int* in_sizes, int n_in,
                              void* d_out, int out_size, void* d_ws, size_t ws_size,
                              hipStream_t stream) {
    const float* x      = (const float*)d_in[0];
    const float* weight = (const float*)d_in[1];
    const float* bias   = (const float*)d_in[2];
    const int*   bits   = (const int*)d_in[3];
    float* out = (float*)d_out;

    float* ws       = (float*)d_ws;
    float* partials = ws;                            // 2304 floats
    float* gstats   = ws + 2304;                     // 8   (fallback only)
    float* coefs    = ws + 2312;                     // 8
    float* tbl      = ws + 2320;                     // 864
    int*   colJ     = (int*)(ws + 3184);             // 864 ints
    unsigned int* wq8 = (unsigned int*)(ws + 4048);  // 6912 u32
    float* wstats   = ws + 10960;                    // 2 floats
    const size_t codes_off   = 43904;                // 64B-aligned
    const size_t codes_bytes = 37748736ull;
    unsigned int* codes = (unsigned int*)((char*)d_ws + codes_off);
    const bool big_ws = ws_size >= codes_off + codes_bytes;

    kAW<<<1179, 256, 0, stream>>>(x, weight, partials, wq8, colJ, wstats);

    dim3 grid(6, 12, 32);
    if (big_ws) {
        kQ_quant<<<32 * 36, 256, 0, stream>>>(x, bits, partials, colJ, wstats, bias, codes, coefs, tbl);
        kC_codes<<<grid, 256, 0, stream>>>(codes, bits, coefs, tbl, wq8, out);
    } else {
        kB2_stats_tbl<<<1, 256, 0, stream>>>(bias, bits, partials, colJ, wstats, gstats, coefs, tbl);
        kC_fused<<<grid, 256, 0, stream>>>(x, bits, gstats, coefs, tbl, wq8, out);
    }
}